// Round 13
// baseline (321.727 us; speedup 1.0000x reference)
//
#include <hip/hip_runtime.h>

// RNNNet: 7-layer tanh RNN, N=65536, T=28, V=28, H=64, 10-class head.
// R13: R11 structure (512 thr / 8 waves, time-quad outer / layer inner,
//      h in registers, wave-private LDS relayout row, R11's exact 2-trans
//      tanh — R12's batched-rcp regressed and is reverted) but weights in a
//      ROTATING 3-LAYER LDS BANK (48KB, restaged from global per bank-visit;
//      weights are L2-resident so restage is cheap) -> LDS 135->69.4KB ->
//      2 blocks/CU -> 4 waves/SIMD. Theory: VALU-issue time (~181us) is
//      work-conserved; the ~86us of unhidden MFMA+LDS-latency stall needs
//      more concurrent waves to hide, not more in-wave ILP (R8/R11/R12 all
//      neutral/negative). Grid 512 = exactly 2 blocks/CU resident.
// GEMMs via mfma_f32_16x16x32_bf16, swapped operands: D[j][s] = W x h^T.

namespace {

typedef __attribute__((ext_vector_type(8))) short bf16x8;
typedef __attribute__((ext_vector_type(4))) float f32x4;
typedef __attribute__((ext_vector_type(4))) unsigned u32x4;

constexpr int WBANK = 0;                // 3-layer bank: 3 x (ih 8KB + hh 8KB)
constexpr int SCR   = 49152;            // 8 wave-private relayout rows (16KB)
constexpr int WCL   = 65536;            // Wc padded [16][64] bf16 (2KB)
constexpr int BIA   = 67584;            // (bih+bhh)*K f32 [7][64] (1792B)
constexpr int BCV   = 69376;            // bc f32 padded [16]
constexpr int LDS_TOTAL = 69440;        // <= 81920 -> 2 blocks/CU

constexpr float TANH_K = 2.8853900817779268f;   // 2/ln(2)

// input pre-scaled by 2/ln2: tanh(x) = 1 - 2/(2^a + 1). 1-ulp HW ops, no bias.
__device__ __forceinline__ float tanh_pre(float a) {
    float z = __builtin_amdgcn_exp2f(a);
    return fmaf(-2.f, __builtin_amdgcn_rcpf(z + 1.f), 1.f);
}
__device__ __forceinline__ unsigned cvt_pk(float a, float b) {
    unsigned r;                              // lo=bf16(a), hi=bf16(b), RNE
    asm("v_cvt_pk_bf16_f32 %0, %1, %2" : "=v"(r) : "v"(a), "v"(b));
    return r;
}
__device__ __forceinline__ int4 pack8s(const float* v, float s) {
    return make_int4((int)cvt_pk(v[0] * s, v[1] * s), (int)cvt_pk(v[2] * s, v[3] * s),
                     (int)cvt_pk(v[4] * s, v[5] * s), (int)cvt_pk(v[6] * s, v[7] * s));
}
__device__ __forceinline__ bf16x8 pk8(float4 a, float4 b) {
    u32x4 t;
    t[0] = cvt_pk(a.x, a.y); t[1] = cvt_pk(a.z, a.w);
    t[2] = cvt_pk(b.x, b.y); t[3] = cvt_pk(b.z, b.w);
    return __builtin_bit_cast(bf16x8, t);
}

} // namespace

__global__ void __launch_bounds__(512, 1)
rnn_fused(const float* __restrict__ x,    const float* __restrict__ Wih0,
          const float* __restrict__ Wih,  const float* __restrict__ Whh,
          const float* __restrict__ bih,  const float* __restrict__ bhh,
          const float* __restrict__ Wc,   const float* __restrict__ bc,
          float* __restrict__ out)
{
    extern __shared__ char smem[];
    const int tid  = threadIdx.x;
    const int lane = tid & 63;
    const int wid  = tid >> 6;          // wave 0..7
    const int sl   = lane & 15;         // seq-in-wave / frag row
    const int g    = lane >> 4;         // lane group 0..3
    const int swzS = (sl & 7) << 4;     // LDS row XOR swizzle
    const int seqbase = blockIdx.x * 128 + wid * 16;

    const int rd0 = (g * 16) ^ swzS;        // B-frag k = g*8..g*8+7
    const int rd1 = (64 + g * 16) ^ swzS;   // B-frag k = 32+g*8..
    int wro[4];
#pragma unroll
    for (int jt = 0; jt < 4; ++jt) wro[jt] = (jt * 32 + g * 8) ^ swzS;
    const int scrw = SCR + wid * 2048 + sl * 128;   // wave-private relayout row

    // staging coordinates (used for every bank restage)
    const int js  = tid >> 3, k0s = (tid & 7) * 8;
    const int wzs = (k0s * 2) ^ ((js & 7) << 4);

    // ------------- one-time resident staging: Wc + biases -------------
    if (tid < 128) { // Wc zero-padded [16][64] (UNscaled: no tanh after)
        int c = tid >> 3, k0 = (tid & 7) * 8;
        float v[8];
#pragma unroll
        for (int e = 0; e < 8; ++e) v[e] = (c < 10) ? Wc[c * 64 + k0 + e] : 0.f;
        *(int4*)(smem + WCL + c * 128 + ((k0 * 2) ^ ((c & 7) << 4))) = pack8s(v, 1.f);
    }
    if (tid < 448) *(float*)(smem + BIA + tid * 4) = (bih[tid] + bhh[tid]) * TANH_K;
    if (tid < 16)  *(float*)(smem + BCV + tid * 4) = (tid < 10) ? bc[tid] : 0.f;
    // visibility ordered by the first bank barrier below

    // ------------- main loop: time-quad outer, bank/layer inner -------------
    const bf16x8 zf = {};
    bf16x8 hb0[7], hb1[7];          // h(l, t-1) B-frag pair (static indices!)
#pragma unroll
    for (int l = 0; l < 7; ++l) { hb0[l] = zf; hb1[l] = zf; }

    const float* xr = x + (size_t)(seqbase + sl) * 784 + g * 8;
    const float4 z4 = make_float4(0.f, 0.f, 0.f, 0.f);

#pragma unroll 1
    for (int tq = 0; tq < 7; ++tq) {
        // x B-frags for t = 4tq..4tq+3, straight from global.
        // g=3 upper half (k=28..31) forced zero: in-bounds & kills pad.
        const float* p0 = xr + tq * 112;
        bf16x8 xf[4];
#pragma unroll
        for (int s = 0; s < 4; ++s) {
            float4 a0 = *(const float4*)(p0 + s * 28);
            float4 a1 = (g < 3) ? *(const float4*)(p0 + s * 28 + 4) : z4;
            xf[s] = pk8(a0, a1);
        }

        bf16x8 itA[4], itB[4];      // layer-(l-1) outputs for the 4 steps

#pragma unroll                      // banks {0,1,2}, {3,4,5}, {6}
        for (int b = 0; b < 3; ++b) {
            const int L0 = 3 * b;
            const int NB = (b == 2) ? 1 : 3;

            __syncthreads();        // all waves done reading previous bank
            // ---- restage bank: layers L0..L0+NB-1 (weights L2-resident) ----
#pragma unroll
            for (int dl = 0; dl < NB; ++dl) {
                const int l = L0 + dl;
                float v[8];
                if (l == 0) {       // Wih0 zero-padded [64][28->64]
#pragma unroll
                    for (int e = 0; e < 8; ++e)
                        v[e] = (k0s + e < 28) ? Wih0[js * 28 + k0s + e] : 0.f;
                } else {
                    const float* src = Wih + (size_t)(l - 1) * 4096 + js * 64 + k0s;
                    float4 a4 = *(const float4*)(src);
                    float4 b4 = *(const float4*)(src + 4);
                    v[0]=a4.x; v[1]=a4.y; v[2]=a4.z; v[3]=a4.w;
                    v[4]=b4.x; v[5]=b4.y; v[6]=b4.z; v[7]=b4.w;
                }
                *(int4*)(smem + WBANK + dl * 16384 + js * 128 + wzs) = pack8s(v, TANH_K);
                const float* srh = Whh + (size_t)l * 4096 + js * 64 + k0s;
                float4 a4 = *(const float4*)(srh);
                float4 b4 = *(const float4*)(srh + 4);
                float w[8] = {a4.x, a4.y, a4.z, a4.w, b4.x, b4.y, b4.z, b4.w};
                *(int4*)(smem + WBANK + dl * 16384 + 8192 + js * 128 + wzs) = pack8s(w, TANH_K);
            }
            __syncthreads();        // bank visible

#pragma unroll                      // layers within the bank (static l)
            for (int dl = 0; dl < NB; ++dl) {
                const int l  = L0 + dl;
                const int wb = WBANK + dl * 16384;
                bf16x8 wi0[4], wi1[4], wh0[4], wh1[4];
                f32x4  bs[4];
#pragma unroll
                for (int jt = 0; jt < 4; ++jt) {
                    const int ro = wb + (jt * 16 + sl) * 128;
                    wi0[jt] = *(const bf16x8*)(smem + ro + rd0);
                    if (l) wi1[jt] = *(const bf16x8*)(smem + ro + rd1); // l=0: zero cols
                    wh0[jt] = *(const bf16x8*)(smem + ro + 8192 + rd0);
                    wh1[jt] = *(const bf16x8*)(smem + ro + 8192 + rd1);
                    bs[jt]  = *(const f32x4*)(smem + BIA + l * 256 + jt * 64 + g * 16);
                }
                bf16x8 hp0 = hb0[l], hp1 = hb1[l];   // h(l, t-1)

#pragma unroll                      // 4 serial timesteps sharing the weights
                for (int s = 0; s < 4; ++s) {
                    const bf16x8 i0 = l ? itA[s] : xf[s];
                    const bf16x8 i1 = l ? itB[s] : zf;
#pragma unroll
                    for (int jt = 0; jt < 4; ++jt) {
                        f32x4 a = bs[jt];   // bias as mfma C-in
                        a = __builtin_amdgcn_mfma_f32_16x16x32_bf16(wi0[jt], i0, a, 0, 0, 0);
                        if (l) a = __builtin_amdgcn_mfma_f32_16x16x32_bf16(wi1[jt], i1, a, 0, 0, 0);
                        a = __builtin_amdgcn_mfma_f32_16x16x32_bf16(wh0[jt], hp0, a, 0, 0, 0);
                        a = __builtin_amdgcn_mfma_f32_16x16x32_bf16(wh1[jt], hp1, a, 0, 0, 0);
                        unsigned q0 = cvt_pk(tanh_pre(a[0]), tanh_pre(a[1]));
                        unsigned q1 = cvt_pk(tanh_pre(a[2]), tanh_pre(a[3]));
                        *(int2*)(smem + scrw + wro[jt]) = make_int2((int)q0, (int)q1);
                    }
                    hp0 = *(const bf16x8*)(smem + scrw + rd0);  // h(l,t) B-frag
                    hp1 = *(const bf16x8*)(smem + scrw + rd1);
                    itA[s] = hp0;   // becomes layer-(l+1)'s input for step s
                    itB[s] = hp1;
                }
                hb0[l] = hp0; hb1[l] = hp1;          // carry h(l, t_last)
            }
        }
    }

    // ---------------- classifier: out = h6(t=27) @ Wc^T + bc ----------------
    {
        const int ro = WCL + sl * 128;                   // A row = class c = sl
        bf16x8 w0 = *(const bf16x8*)(smem + ro + rd0);
        bf16x8 w1 = *(const bf16x8*)(smem + ro + rd1);
        f32x4 o = {0.f, 0.f, 0.f, 0.f};
        o = __builtin_amdgcn_mfma_f32_16x16x32_bf16(w0, hb0[6], o, 0, 0, 0);
        o = __builtin_amdgcn_mfma_f32_16x16x32_bf16(w1, hb1[6], o, 0, 0, 0);
        f32x4 bb = *(const f32x4*)(smem + BCV + g * 16);
#pragma unroll
        for (int r = 0; r < 4; ++r) {
            const int c = g * 4 + r;
            if (c < 10)
                out[(size_t)(seqbase + sl) * 10 + c] = o[r] + bb[r];
        }
    }
}

extern "C" void kernel_launch(void* const* d_in, const int* in_sizes, int n_in,
                              void* d_out, int out_size, void* d_ws, size_t ws_size,
                              hipStream_t stream) {
    (void)in_sizes; (void)n_in; (void)d_ws; (void)ws_size; (void)out_size;
    hipFuncSetAttribute((const void*)rnn_fused,
                        hipFuncAttributeMaxDynamicSharedMemorySize, LDS_TOTAL);
    rnn_fused<<<dim3(512), dim3(512), LDS_TOTAL, stream>>>(
        (const float*)d_in[0], (const float*)d_in[1], (const float*)d_in[2],
        (const float*)d_in[3], (const float*)d_in[4], (const float*)d_in[5],
        (const float*)d_in[6], (const float*)d_in[7], (float*)d_out);
}

// Round 14
// 267.565 us; speedup vs baseline: 1.2024x; 1.2024x over previous
//
#include <hip/hip_runtime.h>

// RNNNet: 7-layer tanh RNN, N=65536, T=28, V=28, H=64, 10-class head.
// R14 = R11 exactly (measured optimum, 267.6us): 512 thr / 8 waves, time-quad
// outer / layer inner, barrier-free main loop, all weights LDS-resident,
// h carried in registers, wave-private 2KB LDS relayout row, exact 2-trans
// tanh (exp2+rcp; 1-ulp, zero bias).
// Adjudicated dead ends (keep for the record):
//   occupancy: 2x512-thr blocks co-reside only at VGPR<=64 (R4 vs R5/R6/R13);
//     frame needs ~116 -> 2 waves/SIMD is structural. 1024-thr forces VGPR=64
//     (R9/R10, two knobs). Rotating W-bank + barriers regressed (R13).
//   in-wave ILP x2: neutral (R8). Weight-LDS reads /2: neutral (R11 vs R7).
//   batched-rcp tanh (-12 trans, +80 VALU): regressed 18% (R12).
//   deg-5 poly tanh: signed 5e-5 bias accumulates over 196 steps, fails (R3).
// Remaining gap vs ~180-220us VALU/trans floor needs >2 waves/SIMD, which
// this register frame cannot reach on this toolchain.
// GEMMs via mfma_f32_16x16x32_bf16, swapped operands: D[j][s] = W x h^T.

namespace {

typedef __attribute__((ext_vector_type(8))) short bf16x8;
typedef __attribute__((ext_vector_type(4))) float f32x4;
typedef __attribute__((ext_vector_type(4))) unsigned u32x4;

constexpr int WST = 0;                  // 7 layers x (ih 8KB + hh 8KB) bf16 swz
constexpr int SCR = 7 * 16384;          // 114688: 8 wave-private relayout rows
constexpr int WCL = SCR + 8 * 2048;     // 131072: Wc padded [16][64] bf16
constexpr int BIA = WCL + 2048;         // 133120: (bih+bhh)*K f32 [7][64]
constexpr int BCV = BIA + 1792;         // 134912: bc f32 padded [16]
constexpr int LDS_TOTAL = BCV + 64;     // 134976 (< 163840, 1 block/CU)

constexpr float TANH_K = 2.8853900817779268f;   // 2/ln(2)

// input pre-scaled by 2/ln2: tanh(x) = 1 - 2/(2^a + 1). 1-ulp HW ops, no bias.
__device__ __forceinline__ float tanh_pre(float a) {
    float z = __builtin_amdgcn_exp2f(a);
    return fmaf(-2.f, __builtin_amdgcn_rcpf(z + 1.f), 1.f);
}
__device__ __forceinline__ unsigned cvt_pk(float a, float b) {
    unsigned r;                              // lo=bf16(a), hi=bf16(b), RNE
    asm("v_cvt_pk_bf16_f32 %0, %1, %2" : "=v"(r) : "v"(a), "v"(b));
    return r;
}
__device__ __forceinline__ int4 pack8s(const float* v, float s) {
    return make_int4((int)cvt_pk(v[0] * s, v[1] * s), (int)cvt_pk(v[2] * s, v[3] * s),
                     (int)cvt_pk(v[4] * s, v[5] * s), (int)cvt_pk(v[6] * s, v[7] * s));
}
__device__ __forceinline__ bf16x8 pk8(float4 a, float4 b) {
    u32x4 t;
    t[0] = cvt_pk(a.x, a.y); t[1] = cvt_pk(a.z, a.w);
    t[2] = cvt_pk(b.x, b.y); t[3] = cvt_pk(b.z, b.w);
    return __builtin_bit_cast(bf16x8, t);
}

} // namespace

__global__ void __launch_bounds__(512, 1)
rnn_fused(const float* __restrict__ x,    const float* __restrict__ Wih0,
          const float* __restrict__ Wih,  const float* __restrict__ Whh,
          const float* __restrict__ bih,  const float* __restrict__ bhh,
          const float* __restrict__ Wc,   const float* __restrict__ bc,
          float* __restrict__ out)
{
    extern __shared__ char smem[];
    const int tid  = threadIdx.x;
    const int lane = tid & 63;
    const int wid  = tid >> 6;          // wave 0..7
    const int sl   = lane & 15;         // seq-in-wave / frag row
    const int g    = lane >> 4;         // lane group 0..3
    const int swzS = (sl & 7) << 4;     // LDS row XOR swizzle
    const int seqbase = blockIdx.x * 128 + wid * 16;

    const int rd0 = (g * 16) ^ swzS;        // B-frag k = g*8..g*8+7
    const int rd1 = (64 + g * 16) ^ swzS;   // B-frag k = 32+g*8..
    int wro[4];
#pragma unroll
    for (int jt = 0; jt < 4; ++jt) wro[jt] = (jt * 32 + g * 8) ^ swzS;
    const int scrw = SCR + wid * 2048 + sl * 128;   // wave-private relayout row

    // ---------------- one-time staging: ALL weights -> LDS ----------------
    {
        const int j = tid >> 3, k0 = (tid & 7) * 8;
        const int wz = (k0 * 2) ^ ((j & 7) << 4);
#pragma unroll
        for (int l = 0; l < 7; ++l) {
            float v[8];
            if (l == 0) {   // Wih0 zero-padded [64][28->64]
#pragma unroll
                for (int e = 0; e < 8; ++e)
                    v[e] = (k0 + e < 28) ? Wih0[j * 28 + k0 + e] : 0.f;
            } else {
                const float* src = Wih + (size_t)(l - 1) * 4096 + j * 64 + k0;
                float4 a4 = *(const float4*)(src);
                float4 b4 = *(const float4*)(src + 4);
                v[0]=a4.x; v[1]=a4.y; v[2]=a4.z; v[3]=a4.w;
                v[4]=b4.x; v[5]=b4.y; v[6]=b4.z; v[7]=b4.w;
            }
            *(int4*)(smem + WST + l * 16384 + j * 128 + wz) = pack8s(v, TANH_K);
            const float* srh = Whh + (size_t)l * 4096 + j * 64 + k0;
            float4 a4 = *(const float4*)(srh);
            float4 b4 = *(const float4*)(srh + 4);
            float w[8] = {a4.x, a4.y, a4.z, a4.w, b4.x, b4.y, b4.z, b4.w};
            *(int4*)(smem + WST + l * 16384 + 8192 + j * 128 + wz) = pack8s(w, TANH_K);
        }
    }
    if (tid < 128) { // Wc zero-padded [16][64] (UNscaled: no tanh after)
        int c = tid >> 3, k0 = (tid & 7) * 8;
        float v[8];
#pragma unroll
        for (int e = 0; e < 8; ++e) v[e] = (c < 10) ? Wc[c * 64 + k0 + e] : 0.f;
        *(int4*)(smem + WCL + c * 128 + ((k0 * 2) ^ ((c & 7) << 4))) = pack8s(v, 1.f);
    }
    if (tid < 448) *(float*)(smem + BIA + tid * 4) = (bih[tid] + bhh[tid]) * TANH_K;
    if (tid < 16)  *(float*)(smem + BCV + tid * 4) = (tid < 10) ? bc[tid] : 0.f;
    __syncthreads();    // the ONLY barrier; main loop is wave-independent

    // ------------- main loop: time-QUAD outer, layer inner -------------
    const bf16x8 zf = {};
    bf16x8 hb0[7], hb1[7];          // h(l, t-1) B-frag pair (static indices!)
#pragma unroll
    for (int l = 0; l < 7; ++l) { hb0[l] = zf; hb1[l] = zf; }

    const float* xr = x + (size_t)(seqbase + sl) * 784 + g * 8;
    const float4 z4 = make_float4(0.f, 0.f, 0.f, 0.f);

#pragma unroll 1
    for (int tq = 0; tq < 7; ++tq) {
        // x B-frags for t = 4tq .. 4tq+3, straight from global.
        // g=3 upper half (k=28..31) forced zero: in-bounds & kills pad.
        const float* p0 = xr + tq * 112;
        bf16x8 xf[4];
#pragma unroll
        for (int s = 0; s < 4; ++s) {
            float4 a0 = *(const float4*)(p0 + s * 28);
            float4 a1 = (g < 3) ? *(const float4*)(p0 + s * 28 + 4) : z4;
            xf[s] = pk8(a0, a1);
        }

        bf16x8 itA[4], itB[4];      // layer-(l-1) outputs for the 4 steps

#pragma unroll                      // FULL unroll: hb[l] + LDS offsets static
        for (int l = 0; l < 7; ++l) {
            const int wb = WST + l * 16384;
            bf16x8 wi0[4], wi1[4], wh0[4], wh1[4];
            f32x4  bs[4];
#pragma unroll
            for (int jt = 0; jt < 4; ++jt) {
                const int ro = wb + (jt * 16 + sl) * 128;
                wi0[jt] = *(const bf16x8*)(smem + ro + rd0);
                if (l) wi1[jt] = *(const bf16x8*)(smem + ro + rd1); // l=0: zero cols
                wh0[jt] = *(const bf16x8*)(smem + ro + 8192 + rd0);
                wh1[jt] = *(const bf16x8*)(smem + ro + 8192 + rd1);
                bs[jt]  = *(const f32x4*)(smem + BIA + l * 256 + jt * 64 + g * 16);
            }
            bf16x8 hp0 = hb0[l], hp1 = hb1[l];   // h(l, t-1)

#pragma unroll                      // 4 serial timesteps sharing the weights
            for (int s = 0; s < 4; ++s) {
                const bf16x8 i0 = l ? itA[s] : xf[s];
                const bf16x8 i1 = l ? itB[s] : zf;
#pragma unroll
                for (int jt = 0; jt < 4; ++jt) {
                    f32x4 a = bs[jt];   // bias as mfma C-in
                    a = __builtin_amdgcn_mfma_f32_16x16x32_bf16(wi0[jt], i0, a, 0, 0, 0);
                    if (l) a = __builtin_amdgcn_mfma_f32_16x16x32_bf16(wi1[jt], i1, a, 0, 0, 0);
                    a = __builtin_amdgcn_mfma_f32_16x16x32_bf16(wh0[jt], hp0, a, 0, 0, 0);
                    a = __builtin_amdgcn_mfma_f32_16x16x32_bf16(wh1[jt], hp1, a, 0, 0, 0);
                    unsigned q0 = cvt_pk(tanh_pre(a[0]), tanh_pre(a[1]));
                    unsigned q1 = cvt_pk(tanh_pre(a[2]), tanh_pre(a[3]));
                    *(int2*)(smem + scrw + wro[jt]) = make_int2((int)q0, (int)q1);
                }
                hp0 = *(const bf16x8*)(smem + scrw + rd0);  // h(l,t) B-frag
                hp1 = *(const bf16x8*)(smem + scrw + rd1);
                itA[s] = hp0;       // becomes layer-(l+1)'s input for step s
                itB[s] = hp1;
            }
            hb0[l] = hp0; hb1[l] = hp1;          // carry h(l, t_last)
        }
    }

    // ---------------- classifier: out = h6(t=27) @ Wc^T + bc ----------------
    {
        const int ro = WCL + sl * 128;                   // A row = class c = sl
        bf16x8 w0 = *(const bf16x8*)(smem + ro + rd0);
        bf16x8 w1 = *(const bf16x8*)(smem + ro + rd1);
        f32x4 o = {0.f, 0.f, 0.f, 0.f};
        o = __builtin_amdgcn_mfma_f32_16x16x32_bf16(w0, hb0[6], o, 0, 0, 0);
        o = __builtin_amdgcn_mfma_f32_16x16x32_bf16(w1, hb1[6], o, 0, 0, 0);
        f32x4 bb = *(const f32x4*)(smem + BCV + g * 16);
#pragma unroll
        for (int r = 0; r < 4; ++r) {
            const int c = g * 4 + r;
            if (c < 10)
                out[(size_t)(seqbase + sl) * 10 + c] = o[r] + bb[r];
        }
    }
}

extern "C" void kernel_launch(void* const* d_in, const int* in_sizes, int n_in,
                              void* d_out, int out_size, void* d_ws, size_t ws_size,
                              hipStream_t stream) {
    (void)in_sizes; (void)n_in; (void)d_ws; (void)ws_size; (void)out_size;
    hipFuncSetAttribute((const void*)rnn_fused,
                        hipFuncAttributeMaxDynamicSharedMemorySize, LDS_TOTAL);
    rnn_fused<<<dim3(512), dim3(512), LDS_TOTAL, stream>>>(
        (const float*)d_in[0], (const float*)d_in[1], (const float*)d_in[2],
        (const float*)d_in[3], (const float*)d_in[4], (const float*)d_in[5],
        (const float*)d_in[6], (const float*)d_in[7], (float*)d_out);
}